// Round 1
// baseline (241.051 us; speedup 1.0000x reference)
//
#include <hip/hip_runtime.h>

#define KS 3
#define NG 2
#define CIN 64
#define OC 18          // NG*KS*KS
#define NB 4
#define H 256
#define W 256
#define OH 128
#define OW 128
#define EPS 1e-5f

// ws layout (floats):
//   [0..17]   sum
//   [18..35]  sumsq
//   [36..53]  scale
//   [54..71]  shift
//   [256 ...] sigma_raw [NB][OC][H][W]  (4*18*256*256 = 4,718,592 floats)

__device__ __forceinline__ int refl(int i, int n) {
    if (i < 0) i = -i;
    if (i >= n) i = 2 * n - 2 - i;
    return i;
}

// ---------------------------------------------------------------------------
// Kernel A: conv(x_reflectpad, w) -> sigma_raw  [NB][OC][H][W]
// 32x32 pixel tile per block, 256 threads, 2x2 pixels per thread.
// ---------------------------------------------------------------------------
__global__ __launch_bounds__(256) void conv_kernel(
        const float* __restrict__ x, const float* __restrict__ wgt,
        float* __restrict__ sigma)
{
    __shared__ float4 w_lds[CIN * OC * 3];   // [ci][oc][3xfloat4] (9 weights padded to 12)
    __shared__ float  xtile[34][34];

    const int tid = threadIdx.x;
    const int tx = tid & 15, ty = tid >> 4;
    const int bx = blockIdx.x, by = blockIdx.y, n = blockIdx.z;

    // stage all weights: wgt[(oc*CIN+ci)*9 + k] -> w_lds[(ci*OC+oc)*3 + q]
    for (int i = tid; i < CIN * OC * 3; i += 256) {
        int ci_oc = i / 3, q = i - ci_oc * 3;
        int ci = ci_oc / OC, oc = ci_oc - ci * OC;
        const float* src = wgt + (oc * CIN + ci) * 9 + q * 4;
        float4 v;
        v.x = src[0];
        v.y = (q * 4 + 1 < 9) ? src[1] : 0.f;
        v.z = (q * 4 + 2 < 9) ? src[2] : 0.f;
        v.w = (q * 4 + 3 < 9) ? src[3] : 0.f;
        w_lds[i] = v;
    }

    float acc[4][OC];
#pragma unroll
    for (int p = 0; p < 4; p++)
#pragma unroll
        for (int oc = 0; oc < OC; oc++) acc[p][oc] = 0.f;

    const int h0 = by * 32, w0 = bx * 32;

    for (int ci = 0; ci < CIN; ci++) {
        __syncthreads();
        // stage 34x34 reflected x tile for this input channel
        const float* xp = x + ((size_t)(n * CIN + ci)) * H * W;
        for (int i = tid; i < 34 * 34; i += 256) {
            int r = i / 34, c = i - r * 34;
            int gh = refl(h0 + r - 1, H);
            int gw = refl(w0 + c - 1, W);
            ((float*)xtile)[i] = xp[gh * W + gw];
        }
        __syncthreads();

        // load 4x4 window for this thread's 2x2 pixels
        float xv[4][4];
#pragma unroll
        for (int rr = 0; rr < 4; rr++) {
            const float2* rp = (const float2*)&xtile[ty * 2 + rr][tx * 2];
            float2 a = rp[0], b = rp[1];
            xv[rr][0] = a.x; xv[rr][1] = a.y; xv[rr][2] = b.x; xv[rr][3] = b.y;
        }

        const int wbase = ci * OC * 3;
#pragma unroll
        for (int oc = 0; oc < OC; oc++) {
            float4 w0v = w_lds[wbase + oc * 3 + 0];
            float4 w1v = w_lds[wbase + oc * 3 + 1];
            float  w8  = w_lds[wbase + oc * 3 + 2].x;
            float wk[9] = {w0v.x, w0v.y, w0v.z, w0v.w, w1v.x, w1v.y, w1v.z, w1v.w, w8};
#pragma unroll
            for (int pr = 0; pr < 2; pr++)
#pragma unroll
                for (int pc = 0; pc < 2; pc++) {
#pragma unroll
                    for (int kh = 0; kh < 3; kh++)
#pragma unroll
                        for (int kw = 0; kw < 3; kw++)
                            acc[pr * 2 + pc][oc] = fmaf(xv[pr + kh][pc + kw], wk[kh * 3 + kw],
                                                        acc[pr * 2 + pc][oc]);
                }
        }
    }

    // write sigma: per (oc, pixel-row) a float2 (two adjacent columns)
#pragma unroll
    for (int oc = 0; oc < OC; oc++) {
#pragma unroll
        for (int pr = 0; pr < 2; pr++) {
            int py = h0 + ty * 2 + pr;
            int px = w0 + tx * 2;
            float2 st = make_float2(acc[pr * 2 + 0][oc], acc[pr * 2 + 1][oc]);
            *(float2*)(sigma + ((size_t)(n * OC + oc) * H + py) * W + px) = st;
        }
    }
}

// ---------------------------------------------------------------------------
// Kernel A2: per-channel sum / sumsq over sigma_raw (N,H,W axes)
// grid = NB*OC*8 blocks; each block reduces 8192 elements of one plane chunk.
// ---------------------------------------------------------------------------
__global__ __launch_bounds__(256) void stats_kernel(
        const float* __restrict__ sigma, float* __restrict__ stats)
{
    int plane = blockIdx.x >> 3, chunk = blockIdx.x & 7;
    const float4* p = (const float4*)(sigma + (size_t)plane * H * W) + chunk * 2048;
    float s = 0.f, ss = 0.f;
    for (int i = threadIdx.x; i < 2048; i += 256) {
        float4 v = p[i];
        s  += v.x + v.y + v.z + v.w;
        ss += v.x * v.x + v.y * v.y + v.z * v.z + v.w * v.w;
    }
#pragma unroll
    for (int off = 32; off > 0; off >>= 1) {
        s  += __shfl_down(s, off);
        ss += __shfl_down(ss, off);
    }
    __shared__ float red[8];
    int wid = threadIdx.x >> 6, lane = threadIdx.x & 63;
    if (lane == 0) { red[wid] = s; red[4 + wid] = ss; }
    __syncthreads();
    if (threadIdx.x == 0) {
        float S  = red[0] + red[1] + red[2] + red[3];
        float SS = red[4] + red[5] + red[6] + red[7];
        int ch = plane % OC;
        atomicAdd(&stats[ch], S);
        atomicAdd(&stats[18 + ch], SS);
    }
}

// ---------------------------------------------------------------------------
// Kernel B: finalize BN -> scale/shift
// ---------------------------------------------------------------------------
__global__ void bn_kernel(const float* __restrict__ gamma,
                          const float* __restrict__ beta,
                          float* __restrict__ stats)
{
    int t = threadIdx.x;
    if (t < OC) {
        float cnt = (float)NB * H * W;
        float mean = stats[t] / cnt;
        float var  = stats[18 + t] / cnt - mean * mean;
        float sc   = gamma[t] * rsqrtf(var + EPS);
        stats[36 + t] = sc;
        stats[54 + t] = beta[t] - mean * sc;
    }
}

// ---------------------------------------------------------------------------
// Kernel C: BN-affine + softmax(18) at strided pixels, then 9-tap adaptive
// aggregation, write out [NB][CIN][OH][OW].
// block: 256 threads handles (n, oh, 16-channel chunk) for all 128 ow.
// ---------------------------------------------------------------------------
__global__ __launch_bounds__(256) void out_kernel(
        const float* __restrict__ x, const float* __restrict__ sigma,
        const float* __restrict__ stats, float* __restrict__ out)
{
    __shared__ float p_lds[OC][OW];   // 18*128*4B = 9 KB

    const int oh = blockIdx.x;
    const int n  = blockIdx.y >> 2;
    const int c0 = (blockIdx.y & 3) * 16;
    const int h  = 2 * oh;
    const int tid = threadIdx.x;

    // load sigma row (strided cols) + BN affine
    for (int i = tid; i < OC * OW; i += 256) {
        int ch = i >> 7, ow = i & 127;
        float v = sigma[((size_t)(n * OC + ch) * H + h) * W + 2 * ow];
        p_lds[ch][ow] = v * stats[36 + ch] + stats[54 + ch];
    }
    __syncthreads();

    // softmax over 18 channels, one thread per pixel (in-place safe: column-exclusive)
    if (tid < OW) {
        int ow = tid;
        float m = -1e30f;
#pragma unroll
        for (int ch = 0; ch < OC; ch++) m = fmaxf(m, p_lds[ch][ow]);
        float e[OC], sum = 0.f;
#pragma unroll
        for (int ch = 0; ch < OC; ch++) { e[ch] = __expf(p_lds[ch][ow] - m); sum += e[ch]; }
        float inv = 1.f / sum;
#pragma unroll
        for (int ch = 0; ch < OC; ch++) p_lds[ch][ow] = e[ch] * inv;
    }
    __syncthreads();

    // aggregate: 16 channels x 128 ow = 2048 outputs, 8 iterations
    const int ow = tid & 127, cl = tid >> 7;
    for (int it = 0; it < 8; it++) {
        int c = c0 + it * 2 + cl;
        int g = c >> 5;
        const float* xb = x + (size_t)(n * CIN + c) * H * W;
        float a = 0.f;
#pragma unroll
        for (int kh = 0; kh < 3; kh++) {
            int ih = refl(h - 1 + kh, H);
#pragma unroll
            for (int kw = 0; kw < 3; kw++) {
                int iw = refl(2 * ow - 1 + kw, W);
                a = fmaf(xb[ih * W + iw], p_lds[g * 9 + kh * 3 + kw][ow], a);
            }
        }
        out[((size_t)(n * CIN + c) * OH + oh) * OW + ow] = a;
    }
}

// ---------------------------------------------------------------------------
extern "C" void kernel_launch(void* const* d_in, const int* in_sizes, int n_in,
                              void* d_out, int out_size, void* d_ws, size_t ws_size,
                              hipStream_t stream) {
    const float* x     = (const float*)d_in[0];
    const float* cw    = (const float*)d_in[1];
    const float* gamma = (const float*)d_in[2];
    const float* beta  = (const float*)d_in[3];
    float* out = (float*)d_out;
    float* ws  = (float*)d_ws;

    float* stats = ws;          // 256 floats (sum/sumsq/scale/shift)
    float* sigma = ws + 256;    // 4,718,592 floats

    hipMemsetAsync(stats, 0, 256 * sizeof(float), stream);

    dim3 gA(W / 32, H / 32, NB);
    conv_kernel<<<gA, 256, 0, stream>>>(x, cw, sigma);

    stats_kernel<<<NB * OC * 8, 256, 0, stream>>>(sigma, stats);

    bn_kernel<<<1, 64, 0, stream>>>(gamma, beta, stats);

    dim3 gC(OH, NB * 4);
    out_kernel<<<gC, 256, 0, stream>>>(x, sigma, stats, out);
}

// Round 2
// 212.824 us; speedup vs baseline: 1.1326x; 1.1326x over previous
//
#include <hip/hip_runtime.h>

#define KS 3
#define NG 2
#define CIN 64
#define OC 18          // NG*KS*KS
#define NB 4
#define H 256
#define W 256
#define OH 128
#define OW 128
#define EPS 1e-5f

#define TS 16          // conv tile
#define HALO 18        // TS + 2
#define XPITCH 20      // LDS row pitch

// ws layout (floats):
//   [0..17]    sum
//   [18..35]   sumsq
//   [36..53]   scale
//   [54..71]   shift
//   [256 ...]  sigma_raw [NB][OC][H][W]  (4,718,592 floats)
//   [256+4718592 ...] wr: repacked weights [CIN][OC][16]  (18,432 floats)

__device__ __forceinline__ int refl(int i, int n) {
    if (i < 0) i = -i;
    if (i >= n) i = 2 * n - 2 - i;
    return i;
}

// ---------------------------------------------------------------------------
// repack weights: wgt[(oc*CIN+ci)*9 + k] -> wr[(ci*OC+oc)*16 + k]  (pad to 16)
// ---------------------------------------------------------------------------
__global__ void repack_w(const float* __restrict__ wgt, float* __restrict__ wr)
{
    int i = blockIdx.x * 256 + threadIdx.x;
    if (i < CIN * OC * 16) {
        int k = i & 15, cioc = i >> 4;
        int oc = cioc % OC, ci = cioc / OC;
        wr[i] = (k < 9) ? wgt[(oc * CIN + ci) * 9 + k] : 0.f;
    }
}

// ---------------------------------------------------------------------------
// Kernel A: conv(x_reflectpad, w) -> sigma_raw  [NB][OC][H][W]
// 16x16 pixel tile per block, 256 threads, 1 pixel/thread, acc[18].
// Weights via uniform (scalar) loads; x tile double-buffered in LDS.
// ---------------------------------------------------------------------------
__global__ __launch_bounds__(256) void conv_kernel(
        const float* __restrict__ x, const float* __restrict__ wr,
        float* __restrict__ sigma)
{
    __shared__ float xt[2][HALO * XPITCH];   // 2 * 360 floats = 2.9 KB

    const int tid = threadIdx.x;
    const int tx = tid & 15, ty = tid >> 4;
    const int h0 = blockIdx.y * TS, w0 = blockIdx.x * TS;
    const int n = blockIdx.z;

    // precompute staging (element i -> global offset / lds offset), i0=tid, i1=tid+256
    int g0, l0, g1 = 0, l1 = 0;
    {
        int r = tid / HALO, c = tid - r * HALO;
        g0 = refl(h0 + r - 1, H) * W + refl(w0 + c - 1, W);
        l0 = r * XPITCH + c;
    }
    const int i1 = tid + 256;
    const bool v1 = i1 < HALO * HALO;
    if (v1) {
        int r = i1 / HALO, c = i1 - r * HALO;
        g1 = refl(h0 + r - 1, H) * W + refl(w0 + c - 1, W);
        l1 = r * XPITCH + c;
    }

    float acc[OC];
#pragma unroll
    for (int oc = 0; oc < OC; oc++) acc[oc] = 0.f;

    const float* xn = x + (size_t)n * CIN * H * W;

    // prefetch ci=0
    float p0 = xn[g0];
    float p1 = v1 ? xn[g1] : 0.f;

    for (int ci = 0; ci < CIN; ci++) {
        float* buf = xt[ci & 1];
        buf[l0] = p0;
        if (v1) buf[l1] = p1;
        if (ci + 1 < CIN) {
            const float* xp = xn + (size_t)(ci + 1) * H * W;
            p0 = xp[g0];
            p1 = v1 ? xp[g1] : 0.f;
        }
        __syncthreads();

        float xw[9];
#pragma unroll
        for (int kh = 0; kh < 3; kh++)
#pragma unroll
            for (int kw = 0; kw < 3; kw++)
                xw[kh * 3 + kw] = buf[(ty + kh) * XPITCH + tx + kw];

        const float* wc = wr + ci * OC * 16;
#pragma unroll
        for (int oc = 0; oc < OC; oc++) {
            const float* wp = wc + oc * 16;   // uniform address -> s_load
#pragma unroll
            for (int k = 0; k < 9; k++)
                acc[oc] = fmaf(xw[k], wp[k], acc[oc]);
        }
        __syncthreads();
    }

    const int py = h0 + ty, px = w0 + tx;
#pragma unroll
    for (int oc = 0; oc < OC; oc++)
        sigma[((size_t)(n * OC + oc) * H + py) * W + px] = acc[oc];
}

// ---------------------------------------------------------------------------
// Kernel A2: per-channel sum / sumsq over sigma_raw (N,H,W axes)
// ---------------------------------------------------------------------------
__global__ __launch_bounds__(256) void stats_kernel(
        const float* __restrict__ sigma, float* __restrict__ stats)
{
    int plane = blockIdx.x >> 3, chunk = blockIdx.x & 7;
    const float4* p = (const float4*)(sigma + (size_t)plane * H * W) + chunk * 2048;
    float s = 0.f, ss = 0.f;
    for (int i = threadIdx.x; i < 2048; i += 256) {
        float4 v = p[i];
        s  += v.x + v.y + v.z + v.w;
        ss += v.x * v.x + v.y * v.y + v.z * v.z + v.w * v.w;
    }
#pragma unroll
    for (int off = 32; off > 0; off >>= 1) {
        s  += __shfl_down(s, off);
        ss += __shfl_down(ss, off);
    }
    __shared__ float red[8];
    int wid = threadIdx.x >> 6, lane = threadIdx.x & 63;
    if (lane == 0) { red[wid] = s; red[4 + wid] = ss; }
    __syncthreads();
    if (threadIdx.x == 0) {
        float S  = red[0] + red[1] + red[2] + red[3];
        float SS = red[4] + red[5] + red[6] + red[7];
        int ch = plane % OC;
        atomicAdd(&stats[ch], S);
        atomicAdd(&stats[18 + ch], SS);
    }
}

// ---------------------------------------------------------------------------
// Kernel B: finalize BN -> scale/shift
// ---------------------------------------------------------------------------
__global__ void bn_kernel(const float* __restrict__ gamma,
                          const float* __restrict__ beta,
                          float* __restrict__ stats)
{
    int t = threadIdx.x;
    if (t < OC) {
        float cnt = (float)NB * H * W;
        float mean = stats[t] / cnt;
        float var  = stats[18 + t] / cnt - mean * mean;
        float sc   = gamma[t] * rsqrtf(var + EPS);
        stats[36 + t] = sc;
        stats[54 + t] = beta[t] - mean * sc;
    }
}

// ---------------------------------------------------------------------------
// Kernel C: BN-affine + softmax(18) at strided pixels, then 9-tap adaptive
// aggregation, write out [NB][CIN][OH][OW].
// ---------------------------------------------------------------------------
__global__ __launch_bounds__(256) void out_kernel(
        const float* __restrict__ x, const float* __restrict__ sigma,
        const float* __restrict__ stats, float* __restrict__ out)
{
    __shared__ float p_lds[OC][OW];   // 9 KB

    const int oh = blockIdx.x;
    const int n  = blockIdx.y >> 2;
    const int c0 = (blockIdx.y & 3) * 16;
    const int h  = 2 * oh;
    const int tid = threadIdx.x;

    for (int i = tid; i < OC * OW; i += 256) {
        int ch = i >> 7, ow = i & 127;
        float v = sigma[((size_t)(n * OC + ch) * H + h) * W + 2 * ow];
        p_lds[ch][ow] = v * stats[36 + ch] + stats[54 + ch];
    }
    __syncthreads();

    if (tid < OW) {
        int ow = tid;
        float m = -1e30f;
#pragma unroll
        for (int ch = 0; ch < OC; ch++) m = fmaxf(m, p_lds[ch][ow]);
        float e[OC], sum = 0.f;
#pragma unroll
        for (int ch = 0; ch < OC; ch++) { e[ch] = __expf(p_lds[ch][ow] - m); sum += e[ch]; }
        float inv = 1.f / sum;
#pragma unroll
        for (int ch = 0; ch < OC; ch++) p_lds[ch][ow] = e[ch] * inv;
    }
    __syncthreads();

    const int ow = tid & 127, cl = tid >> 7;
    for (int it = 0; it < 8; it++) {
        int c = c0 + it * 2 + cl;
        int g = c >> 5;
        const float* xb = x + (size_t)(n * CIN + c) * H * W;
        float a = 0.f;
#pragma unroll
        for (int kh = 0; kh < 3; kh++) {
            int ih = refl(h - 1 + kh, H);
#pragma unroll
            for (int kw = 0; kw < 3; kw++) {
                int iw = refl(2 * ow - 1 + kw, W);
                a = fmaf(xb[ih * W + iw], p_lds[g * 9 + kh * 3 + kw][ow], a);
            }
        }
        out[((size_t)(n * CIN + c) * OH + oh) * OW + ow] = a;
    }
}

// ---------------------------------------------------------------------------
extern "C" void kernel_launch(void* const* d_in, const int* in_sizes, int n_in,
                              void* d_out, int out_size, void* d_ws, size_t ws_size,
                              hipStream_t stream) {
    const float* x     = (const float*)d_in[0];
    const float* cw    = (const float*)d_in[1];
    const float* gamma = (const float*)d_in[2];
    const float* beta  = (const float*)d_in[3];
    float* out = (float*)d_out;
    float* ws  = (float*)d_ws;

    float* stats = ws;                      // 256 floats
    float* sigma = ws + 256;                // 4,718,592 floats
    float* wrpk  = sigma + (size_t)NB * OC * H * W;  // 18,432 floats

    hipMemsetAsync(stats, 0, 256 * sizeof(float), stream);

    repack_w<<<(CIN * OC * 16 + 255) / 256, 256, 0, stream>>>(cw, wrpk);

    dim3 gA(W / TS, H / TS, NB);
    conv_kernel<<<gA, 256, 0, stream>>>(x, wrpk, sigma);

    stats_kernel<<<NB * OC * 8, 256, 0, stream>>>(sigma, stats);

    bn_kernel<<<1, 64, 0, stream>>>(gamma, beta, stats);

    dim3 gC(OH, NB * 4);
    out_kernel<<<gC, 256, 0, stream>>>(x, sigma, stats, out);
}